// Round 1
// baseline (41.758 us; speedup 1.0000x reference)
//
#include <hip/hip_runtime.h>
#include <stdint.h>

// Gumbel-max sampler, fused single pass.
// score[v] = logits[v]/t - log(max(-log(u[v]), 1e-10))   (non-greedy rows)
// score[v] = logits[v]                                    (greedy rows, t<=1e-10)
// argmax with first-index tie-break == jnp.argmax semantics.

__device__ __forceinline__ uint32_t order_f32(float f) {
    // monotone map float -> uint32 (totally ordered for finite floats)
    uint32_t u = __float_as_uint(f);
    return (u & 0x80000000u) ? ~u : (u | 0x80000000u);
}

__global__ __launch_bounds__(1024) void sampler_kernel(
        const float* __restrict__ logits,
        const float* __restrict__ temps,
        const float* __restrict__ u,
        int* __restrict__ out,
        int V) {
    const int row = blockIdx.x;
    const float t = temps[row];
    const bool greedy = (t <= 1e-10f);
    const float invT = greedy ? 1.0f : (1.0f / t);

    const size_t rowoff = (size_t)row * (size_t)V;
    const float4* lrow = reinterpret_cast<const float4*>(logits + rowoff);
    const float4* urow = reinterpret_cast<const float4*>(u + rowoff);
    const int nvec = V >> 2;  // V divisible by 4 (128256/4 = 32064)

    float best = -__builtin_inff();
    int bidx = 0;

    if (greedy) {
        for (int i = threadIdx.x; i < nvec; i += blockDim.x) {
            float4 lg = lrow[i];
            const int base = i << 2;
            float s0 = lg.x, s1 = lg.y, s2 = lg.z, s3 = lg.w;
            if (s0 > best || (s0 == best && base + 0 < bidx)) { best = s0; bidx = base + 0; }
            if (s1 > best || (s1 == best && base + 1 < bidx)) { best = s1; bidx = base + 1; }
            if (s2 > best || (s2 == best && base + 2 < bidx)) { best = s2; bidx = base + 2; }
            if (s3 > best || (s3 == best && base + 3 < bidx)) { best = s3; bidx = base + 3; }
        }
    } else {
        for (int i = threadIdx.x; i < nvec; i += blockDim.x) {
            float4 lg = lrow[i];
            float4 uv = urow[i];
            const int base = i << 2;
            float s0 = lg.x * invT - logf(fmaxf(-logf(uv.x), 1e-10f));
            float s1 = lg.y * invT - logf(fmaxf(-logf(uv.y), 1e-10f));
            float s2 = lg.z * invT - logf(fmaxf(-logf(uv.z), 1e-10f));
            float s3 = lg.w * invT - logf(fmaxf(-logf(uv.w), 1e-10f));
            if (s0 > best || (s0 == best && base + 0 < bidx)) { best = s0; bidx = base + 0; }
            if (s1 > best || (s1 == best && base + 1 < bidx)) { best = s1; bidx = base + 1; }
            if (s2 > best || (s2 == best && base + 2 < bidx)) { best = s2; bidx = base + 2; }
            if (s3 > best || (s3 == best && base + 3 < bidx)) { best = s3; bidx = base + 3; }
        }
    }

    // pack: high 32 = ordered score, low 32 = ~idx  (max-reduce => first-index tie-break)
    unsigned long long key =
        ((unsigned long long)order_f32(best) << 32) | (unsigned long long)(~(uint32_t)bidx);

    // wave-level reduce (wave = 64 lanes)
    #pragma unroll
    for (int off = 32; off > 0; off >>= 1) {
        unsigned long long other = __shfl_down(key, off, 64);
        if (other > key) key = other;
    }

    __shared__ unsigned long long smax;
    if (threadIdx.x == 0) smax = 0ull;
    __syncthreads();
    if ((threadIdx.x & 63) == 0) {
        atomicMax(&smax, key);
    }
    __syncthreads();
    if (threadIdx.x == 0) {
        out[row] = (int)(~(uint32_t)(smax & 0xffffffffull));
    }
}

extern "C" void kernel_launch(void* const* d_in, const int* in_sizes, int n_in,
                              void* d_out, int out_size, void* d_ws, size_t ws_size,
                              hipStream_t stream) {
    const float* logits = (const float*)d_in[0];
    const float* temps  = (const float*)d_in[1];
    const float* u      = (const float*)d_in[2];
    int* out = (int*)d_out;

    const int B = in_sizes[1];
    const int V = in_sizes[0] / B;

    sampler_kernel<<<B, 1024, 0, stream>>>(logits, temps, u, out, V);
}

// Round 2
// 39.721 us; speedup vs baseline: 1.0513x; 1.0513x over previous
//
#include <hip/hip_runtime.h>
#include <stdint.h>

// Gumbel-max sampler, fused, row-split for occupancy.
// Phase 1: 8 blocks per row, each computes a partial argmax key over V/8 elems.
// Phase 2: 1 tiny block reduces 8 keys/row -> token id.
//
// score'[v] = logits[v]*(invT/ln2) - log2(max(-log2(u[v]), 1e-10/ln2))
// (monotone transform of the reference score; same argmax, incl. per-row consts)
// Greedy rows (t<=1e-10): score'[v] = logits[v].

#define SPLIT 8
#define T1 512

__device__ __forceinline__ uint32_t order_f32(float f) {
    uint32_t u = __float_as_uint(f);
    return (u & 0x80000000u) ? ~u : (u | 0x80000000u);
}

__global__ __launch_bounds__(T1) void sampler_part_kernel(
        const float* __restrict__ logits,
        const float* __restrict__ temps,
        const float* __restrict__ u,
        unsigned long long* __restrict__ ws,
        int V) {
    const int bid = blockIdx.x;
    const int row = bid >> 3;          // / SPLIT
    const int seg = bid & (SPLIT - 1);
    const int chunk = V / SPLIT;       // 16032, divisible by 4
    const int nvec = chunk >> 2;       // 4008 float4 per segment

    const float t = temps[row];
    const bool greedy = (t <= 1e-10f);
    // fold 1/ln2 into the temperature scale (monotone, argmax-invariant)
    const float invT = greedy ? 1.0f : (1.4426950408889634f / t);
    const float CLMP = 1.4426950408889634e-10f;  // 1e-10 / ln2

    const size_t segoff = (size_t)row * (size_t)V + (size_t)seg * chunk;
    const float4* lseg = reinterpret_cast<const float4*>(logits + segoff);
    const float4* useg = reinterpret_cast<const float4*>(u + segoff);
    const int idx0 = seg * chunk;      // global index of segment start within row

    float best = -__builtin_inff();
    int bidx = 0;

    if (greedy) {
        for (int i = threadIdx.x; i < nvec; i += T1) {
            float4 lg = lseg[i];
            const int base = idx0 + (i << 2);
            if (lg.x > best || (lg.x == best && base + 0 < bidx)) { best = lg.x; bidx = base + 0; }
            if (lg.y > best || (lg.y == best && base + 1 < bidx)) { best = lg.y; bidx = base + 1; }
            if (lg.z > best || (lg.z == best && base + 2 < bidx)) { best = lg.z; bidx = base + 2; }
            if (lg.w > best || (lg.w == best && base + 3 < bidx)) { best = lg.w; bidx = base + 3; }
        }
    } else {
        for (int i = threadIdx.x; i < nvec; i += T1) {
            float4 lg = lseg[i];
            float4 uv = useg[i];
            const int base = idx0 + (i << 2);
            float s0 = lg.x * invT - __log2f(fmaxf(-__log2f(uv.x), CLMP));
            float s1 = lg.y * invT - __log2f(fmaxf(-__log2f(uv.y), CLMP));
            float s2 = lg.z * invT - __log2f(fmaxf(-__log2f(uv.z), CLMP));
            float s3 = lg.w * invT - __log2f(fmaxf(-__log2f(uv.w), CLMP));
            if (s0 > best || (s0 == best && base + 0 < bidx)) { best = s0; bidx = base + 0; }
            if (s1 > best || (s1 == best && base + 1 < bidx)) { best = s1; bidx = base + 1; }
            if (s2 > best || (s2 == best && base + 2 < bidx)) { best = s2; bidx = base + 2; }
            if (s3 > best || (s3 == best && base + 3 < bidx)) { best = s3; bidx = base + 3; }
        }
    }

    // pack: high 32 = ordered score, low 32 = ~idx (max => first-index tie-break)
    unsigned long long key =
        ((unsigned long long)order_f32(best) << 32) | (unsigned long long)(~(uint32_t)bidx);

    #pragma unroll
    for (int off = 32; off > 0; off >>= 1) {
        unsigned long long other = __shfl_down(key, off, 64);
        if (other > key) key = other;
    }

    __shared__ unsigned long long smax;
    if (threadIdx.x == 0) smax = 0ull;
    __syncthreads();
    if ((threadIdx.x & 63) == 0) atomicMax(&smax, key);
    __syncthreads();
    if (threadIdx.x == 0) ws[bid] = smax;
}

__global__ __launch_bounds__(256) void sampler_reduce_kernel(
        const unsigned long long* __restrict__ ws,
        int* __restrict__ out) {
    const int row = threadIdx.x;  // 256 rows, one block
    unsigned long long best = ws[row * SPLIT];
    #pragma unroll
    for (int s = 1; s < SPLIT; ++s) {
        unsigned long long k = ws[row * SPLIT + s];
        if (k > best) best = k;
    }
    out[row] = (int)(~(uint32_t)(best & 0xffffffffull));
}

extern "C" void kernel_launch(void* const* d_in, const int* in_sizes, int n_in,
                              void* d_out, int out_size, void* d_ws, size_t ws_size,
                              hipStream_t stream) {
    const float* logits = (const float*)d_in[0];
    const float* temps  = (const float*)d_in[1];
    const float* u      = (const float*)d_in[2];
    int* out = (int*)d_out;
    unsigned long long* ws = (unsigned long long*)d_ws;

    const int B = in_sizes[1];
    const int V = in_sizes[0] / B;

    sampler_part_kernel<<<B * SPLIT, T1, 0, stream>>>(logits, temps, u, ws, V);
    sampler_reduce_kernel<<<1, B, 0, stream>>>(ws, out);
}